// Round 5
// baseline (152.463 us; speedup 1.0000x reference)
//
#include <hip/hip_runtime.h>
#include <math.h>

// ---------------------------------------------------------------------------
// LAMForMTEBSuper: two-timescale decaying associative memory + doc supervector.
//
// Key math: kn is unit-norm => k^T W' = v exactly after each update
// => v_fast == v_slow => flux == 0.1*sigmoid(-0.5) == const (PHI below).
// Heads decouple; recurrence is linear with contraction c1 = (1-PHI)*0.85
// = 0.81791 per step (||I - kk^T||_2 = 1, an orthogonal projector).
// Tokens m steps before the end contribute O(c1^m): start the scan from a
// zero state NWIN tokens before the end. NWIN=128 -> c1^128 ~ 7e-12 relative
// truncation — below fp32 eps, indistinguishable from the exact scan.
// (First-validation choice: rules out truncation as a failure cause; tighten
// to 96/64 after a measured pass margin.)
// ---------------------------------------------------------------------------

#define T_TOK 16384
#define DMODEL 384
#define NHEAD 12
#define NWIN 128          // c1^128 ~ 7e-12: below fp32 eps
#define TPB 4             // tokens per block in proj kernel

#define DF 0.3f
#define PHI 0.03775406687981455f      // 0.1/(1+e^0.5)
#define OMPHI 0.96224593312018545f    // 1-PHI
#define C1 0.81790904315215763f       // 0.85*(1-PHI)

// ws layout: kv buffer [NHEAD][NWIN+1][64] floats at offset 0 (pad row NWIN so
// the scan's prefetch over-read stays in-bounds); Ws output at +512KB.
#define WSOUT_OFF (512 * 1024)

// ---------------------------------------------------------------------------
// K1: project last NWIN tokens, k-normalize per head, write [h][t][k(32)|v(32)].
// 32 blocks x 384 threads; 4 tokens/block staged in LDS (broadcast reads);
// each thread computes one row of BOTH K and V projections (float4 weights).
// ---------------------------------------------------------------------------
__global__ __launch_bounds__(DMODEL) void proj_kernel(
    const float* __restrict__ hidden, const float* __restrict__ key_w,
    const float* __restrict__ value_w, float* __restrict__ kv)
{
    __shared__ float hid[TPB * DMODEL];
    const int tid = threadIdx.x;
    const int b = blockIdx.x;
    const int t0 = T_TOK - NWIN + b * TPB;

#pragma unroll
    for (int r = 0; r < TPB; r++)
        hid[r * DMODEL + tid] = hidden[(size_t)(t0 + r) * DMODEL + tid];
    __syncthreads();

    const int o = tid;          // output row: o = h*32 + i
    const int h = o >> 5;
    const int i = o & 31;

    float ak[TPB] = {0.f, 0.f, 0.f, 0.f};
    float av[TPB] = {0.f, 0.f, 0.f, 0.f};

    const float4* wk4 = reinterpret_cast<const float4*>(key_w + (size_t)o * DMODEL);
    const float4* wv4 = reinterpret_cast<const float4*>(value_w + (size_t)o * DMODEL);
    const float4* h4 = reinterpret_cast<const float4*>(hid);

#pragma unroll 4
    for (int d = 0; d < DMODEL / 4; d++) {
        float4 wk = wk4[d];
        float4 wv = wv4[d];
#pragma unroll
        for (int r = 0; r < TPB; r++) {
            float4 x = h4[r * (DMODEL / 4) + d];   // broadcast LDS read
            ak[r] = fmaf(wk.x, x.x, fmaf(wk.y, x.y, fmaf(wk.z, x.z, fmaf(wk.w, x.w, ak[r]))));
            av[r] = fmaf(wv.x, x.x, fmaf(wv.y, x.y, fmaf(wv.z, x.z, fmaf(wv.w, x.w, av[r]))));
        }
    }

    // k-normalize per (token, head): heads are 32-lane groups (= wave halves),
    // so xor-masks 1..16 stay within the group.
#pragma unroll
    for (int r = 0; r < TPB; r++) {
        float ss = ak[r] * ak[r];
        ss += __shfl_xor(ss, 1);
        ss += __shfl_xor(ss, 2);
        ss += __shfl_xor(ss, 4);
        ss += __shfl_xor(ss, 8);
        ss += __shfl_xor(ss, 16);
        float sc = 1.0f / fmaxf(sqrtf(ss), 1e-12f);
        const int tl = b * TPB + r;
        float* dst = kv + ((size_t)h * (NWIN + 1) + tl) * 64;
        dst[i] = ak[r] * sc;
        dst[32 + i] = av[r];
    }
}

// ---------------------------------------------------------------------------
// K2: per-head sequential scan, 1 wave per head. lane = (v in 0..31, khalf).
// Each lane owns Wf[16], Ws[16] (its k-slice for one v column), all in VGPRs
// with compile-time indexing (rule #20). flux folded into constants:
//   Wf <- DF*Wf + kt*(vt - DF*kWf)
//   Ws <- C1*Ws + kt*(OMPHI*vt - C1*kWs) + PHI*Wf_new
// Next token's k/v prefetched at loop top; unroll 2 lets regalloc rename the
// double-buffer instead of emitting 17 v_mov per step.
// ---------------------------------------------------------------------------
__global__ __launch_bounds__(64) void scan_kernel(
    const float* __restrict__ kv, float* __restrict__ wsout)
{
    const int h = blockIdx.x;
    const int lane = threadIdx.x;
    const int v = lane & 31;
    const int kh = lane >> 5;

    const float* p = kv + (size_t)h * (NWIN + 1) * 64;

    float kt[16];
    float cv;
    {
        const float4* r4 = reinterpret_cast<const float4*>(p) + kh * 4;
        float4 a = r4[0], b = r4[1], c = r4[2], d = r4[3];
        kt[0] = a.x; kt[1] = a.y; kt[2] = a.z; kt[3] = a.w;
        kt[4] = b.x; kt[5] = b.y; kt[6] = b.z; kt[7] = b.w;
        kt[8] = c.x; kt[9] = c.y; kt[10] = c.z; kt[11] = c.w;
        kt[12] = d.x; kt[13] = d.y; kt[14] = d.z; kt[15] = d.w;
        cv = p[32 + v];
    }

    float wf[16], ws[16];
#pragma unroll
    for (int j = 0; j < 16; j++) { wf[j] = 0.f; ws[j] = 0.f; }

#pragma unroll 2
    for (int t = 0; t < NWIN; t++) {
        // Prefetch next token's k-slice and v element (row NWIN is a legal pad;
        // poison bytes there are loaded but never consumed).
        const float* nrow = p + (size_t)(t + 1) * 64;
        const float4* n4 = reinterpret_cast<const float4*>(nrow) + kh * 4;
        float4 na = n4[0], nb = n4[1], nc = n4[2], nd = n4[3];
        float nv = nrow[32 + v];

        // kWf[v], kWs[v]: partial dot over this lane's 16 k's, 2 accums for ILP
        float p0 = 0.f, p1 = 0.f, q0 = 0.f, q1 = 0.f;
#pragma unroll
        for (int j = 0; j < 8; j++) {
            p0 = fmaf(kt[j], wf[j], p0);
            q0 = fmaf(kt[j], ws[j], q0);
        }
#pragma unroll
        for (int j = 8; j < 16; j++) {
            p1 = fmaf(kt[j], wf[j], p1);
            q1 = fmaf(kt[j], ws[j], q1);
        }
        float pf = p0 + p1, ps = q0 + q1;
        float kwf = pf + __shfl_xor(pf, 32);   // combine the two k-halves
        float kws = ps + __shfl_xor(ps, 32);

        float t1 = fmaf(-DF, kwf, cv);            // vt - DF*kWf
        float sv = fmaf(-C1, kws, OMPHI * cv);    // (1-PHI)*vt - C1*kWs

#pragma unroll
        for (int j = 0; j < 16; j++) {
            wf[j] = fmaf(DF, wf[j], kt[j] * t1);                       // Wf_new
            ws[j] = fmaf(C1, ws[j], fmaf(PHI, wf[j], kt[j] * sv));     // uses Wf_new
        }

        kt[0] = na.x; kt[1] = na.y; kt[2] = na.z; kt[3] = na.w;
        kt[4] = nb.x; kt[5] = nb.y; kt[6] = nb.z; kt[7] = nb.w;
        kt[8] = nc.x; kt[9] = nc.y; kt[10] = nc.z; kt[11] = nc.w;
        kt[12] = nd.x; kt[13] = nd.y; kt[14] = nd.z; kt[15] = nd.w;
        cv = nv;
    }

    // Write Ws in reference flatten order: idx = h*1024 + k*32 + v
    float* outp = wsout + (size_t)h * 1024;
#pragma unroll
    for (int j = 0; j < 16; j++)
        outp[(kh * 16 + j) * 32 + v] = ws[j];
}

// ---------------------------------------------------------------------------
// K3: normalize the 12288-float supervector.
// ---------------------------------------------------------------------------
__global__ __launch_bounds__(256) void norm_kernel(
    const float* __restrict__ wsin, float* __restrict__ out)
{
    const int tid = threadIdx.x;
    const float4* in4 = reinterpret_cast<const float4*>(wsin);  // 3072 float4

    float ss = 0.f;
#pragma unroll
    for (int it = 0; it < 12; it++) {
        float4 x = in4[tid + 256 * it];
        ss += x.x * x.x + x.y * x.y + x.z * x.z + x.w * x.w;
    }
    ss += __shfl_xor(ss, 1);
    ss += __shfl_xor(ss, 2);
    ss += __shfl_xor(ss, 4);
    ss += __shfl_xor(ss, 8);
    ss += __shfl_xor(ss, 16);
    ss += __shfl_xor(ss, 32);

    __shared__ float wsum[4];
    if ((tid & 63) == 0) wsum[tid >> 6] = ss;
    __syncthreads();
    float tot = wsum[0] + wsum[1] + wsum[2] + wsum[3];
    float sc = 1.0f / fmaxf(sqrtf(tot), 1e-12f);

#pragma unroll
    for (int it = 0; it < 12; it++) {
        float4 x = in4[tid + 256 * it];
        x.x *= sc; x.y *= sc; x.z *= sc; x.w *= sc;
        reinterpret_cast<float4*>(out)[tid + 256 * it] = x;
    }
}

// ---------------------------------------------------------------------------
extern "C" void kernel_launch(void* const* d_in, const int* in_sizes, int n_in,
                              void* d_out, int out_size, void* d_ws, size_t ws_size,
                              hipStream_t stream)
{
    const float* hidden  = (const float*)d_in[0];
    const float* key_w   = (const float*)d_in[1];
    const float* value_w = (const float*)d_in[2];

    float* kv    = (float*)d_ws;                         // 12*129*64*4 = 387 KB
    float* wsout = (float*)((char*)d_ws + WSOUT_OFF);    // 48 KB

    proj_kernel<<<NWIN / TPB, DMODEL, 0, stream>>>(hidden, key_w, value_w, kv);
    scan_kernel<<<NHEAD, 64, 0, stream>>>(kv, wsout);
    norm_kernel<<<1, 256, 0, stream>>>(wsout, (float*)d_out);
}

// Round 6
// 139.467 us; speedup vs baseline: 1.0932x; 1.0932x over previous
//
#include <hip/hip_runtime.h>
#include <math.h>

// ---------------------------------------------------------------------------
// LAMForMTEBSuper: two-timescale decaying associative memory + doc supervector.
//
// Key math: kn is unit-norm => k^T W' = v exactly after each update
// => v_fast == v_slow => flux == 0.1*sigmoid(-0.5) == const (PHI below).
// Heads decouple; recurrence is linear with contraction c1 = (1-PHI)*0.85
// = 0.81791 per step (||I - kk^T||_2 = 1, an orthogonal projector).
// Tokens m steps before the end contribute O(c1^m): start from zero state
// NWIN tokens before the end. NWIN=80 -> c1^80 ~ 1e-7 relative truncation
// -> ~3e-8 absolute on the normalized output, negligible vs the measured
// 4.8e-7 fp32 rounding noise (R5 run, NWIN=128, passed).
// ---------------------------------------------------------------------------

#define T_TOK 16384
#define DMODEL 384
#define NHEAD 12
#define NWIN 80           // c1^80 ~ 1e-7 rel: ~3e-8 abs on output, negligible

#define DF 0.3f
#define PHI 0.03775406687981455f      // 0.1/(1+e^0.5)
#define OMPHI 0.96224593312018545f    // 1-PHI
#define C1 0.81790904315215763f       // 0.85*(1-PHI)

// ws layout: kv buffer [NHEAD][NWIN+1][64] floats at offset 0 (pad row NWIN so
// the scan's prefetch over-read stays in-bounds); Ws output at +512KB.
#define WSOUT_OFF (512 * 1024)

// ---------------------------------------------------------------------------
// K1 v2: one block per token, 768 threads (12 waves). R5 counters showed v1
// at 1.8% occupancy / 1.8% VALUBusy (latency-bound, 192 waves chip-wide);
// v2 launches 960 waves and gives each thread ONE dot product with 4
// independent accumulator streams (4 concurrent load chains).
// Threads 0..383 compute K rows (waves 0..5), 384..767 V rows (waves 6..11)
// -> the K/V branch is wave-uniform.
// ---------------------------------------------------------------------------
__global__ __launch_bounds__(768) void proj_kernel(
    const float* __restrict__ hidden, const float* __restrict__ key_w,
    const float* __restrict__ value_w, float* __restrict__ kv)
{
    __shared__ float hid[DMODEL];
    const int tid = threadIdx.x;
    const int b = blockIdx.x;                 // token index in window
    const int t = T_TOK - NWIN + b;

    if (tid < DMODEL / 4)
        reinterpret_cast<float4*>(hid)[tid] =
            reinterpret_cast<const float4*>(hidden + (size_t)t * DMODEL)[tid];
    __syncthreads();

    const bool isK = (tid < 384);
    const int row = isK ? tid : tid - 384;    // row in [0,384): h*32+i
    const float* wrow = (isK ? key_w : value_w) + (size_t)row * DMODEL;
    const float4* w4 = reinterpret_cast<const float4*>(wrow);
    const float4* h4 = reinterpret_cast<const float4*>(hid);

    float a0 = 0.f, a1 = 0.f, a2 = 0.f, a3 = 0.f;
#pragma unroll 6
    for (int d = 0; d < 24; d++) {
        float4 w0 = w4[d],      x0 = h4[d];
        float4 w1 = w4[24 + d], x1 = h4[24 + d];
        float4 w2 = w4[48 + d], x2 = h4[48 + d];
        float4 w3 = w4[72 + d], x3 = h4[72 + d];
        a0 = fmaf(w0.x, x0.x, fmaf(w0.y, x0.y, fmaf(w0.z, x0.z, fmaf(w0.w, x0.w, a0))));
        a1 = fmaf(w1.x, x1.x, fmaf(w1.y, x1.y, fmaf(w1.z, x1.z, fmaf(w1.w, x1.w, a1))));
        a2 = fmaf(w2.x, x2.x, fmaf(w2.y, x2.y, fmaf(w2.z, x2.z, fmaf(w2.w, x2.w, a2))));
        a3 = fmaf(w3.x, x3.x, fmaf(w3.y, x3.y, fmaf(w3.z, x3.z, fmaf(w3.w, x3.w, a3))));
    }
    float sum = (a0 + a1) + (a2 + a3);

    const int h = row >> 5;
    const int i = row & 31;
    float* dst = kv + ((size_t)h * (NWIN + 1) + b) * 64;

    if (isK) {
        // k-normalize: each head = 32 consecutive lanes (a wave half);
        // xor-masks 1..16 stay within the half.
        float ss = sum * sum;
        ss += __shfl_xor(ss, 1);
        ss += __shfl_xor(ss, 2);
        ss += __shfl_xor(ss, 4);
        ss += __shfl_xor(ss, 8);
        ss += __shfl_xor(ss, 16);
        float sc = 1.0f / fmaxf(sqrtf(ss), 1e-12f);
        dst[i] = sum * sc;
    } else {
        dst[32 + i] = sum;
    }
}

// ---------------------------------------------------------------------------
// K2: per-head sequential scan, 1 wave per head. lane = (v in 0..31, khalf).
// Each lane owns Wf[16], Ws[16] (its k-slice for one v column), all in VGPRs
// with compile-time indexing (rule #20). flux folded into constants:
//   Wf <- DF*Wf + kt*(vt - DF*kWf)
//   Ws <- C1*Ws + kt*(OMPHI*vt - C1*kWs) + PHI*Wf_new
// Next token's k/v prefetched at loop top; unroll 2 lets regalloc rename the
// double-buffer instead of emitting 17 v_mov per step.
// ---------------------------------------------------------------------------
__global__ __launch_bounds__(64) void scan_kernel(
    const float* __restrict__ kv, float* __restrict__ wsout)
{
    const int h = blockIdx.x;
    const int lane = threadIdx.x;
    const int v = lane & 31;
    const int kh = lane >> 5;

    const float* p = kv + (size_t)h * (NWIN + 1) * 64;

    float kt[16];
    float cv;
    {
        const float4* r4 = reinterpret_cast<const float4*>(p) + kh * 4;
        float4 a = r4[0], b = r4[1], c = r4[2], d = r4[3];
        kt[0] = a.x; kt[1] = a.y; kt[2] = a.z; kt[3] = a.w;
        kt[4] = b.x; kt[5] = b.y; kt[6] = b.z; kt[7] = b.w;
        kt[8] = c.x; kt[9] = c.y; kt[10] = c.z; kt[11] = c.w;
        kt[12] = d.x; kt[13] = d.y; kt[14] = d.z; kt[15] = d.w;
        cv = p[32 + v];
    }

    float wf[16], ws[16];
#pragma unroll
    for (int j = 0; j < 16; j++) { wf[j] = 0.f; ws[j] = 0.f; }

#pragma unroll 2
    for (int t = 0; t < NWIN; t++) {
        // Prefetch next token's k-slice and v element (row NWIN is a legal pad;
        // poison bytes there are loaded but never consumed).
        const float* nrow = p + (size_t)(t + 1) * 64;
        const float4* n4 = reinterpret_cast<const float4*>(nrow) + kh * 4;
        float4 na = n4[0], nb = n4[1], nc = n4[2], nd = n4[3];
        float nv = nrow[32 + v];

        // kWf[v], kWs[v]: partial dot over this lane's 16 k's, 2 accums for ILP
        float p0 = 0.f, p1 = 0.f, q0 = 0.f, q1 = 0.f;
#pragma unroll
        for (int j = 0; j < 8; j++) {
            p0 = fmaf(kt[j], wf[j], p0);
            q0 = fmaf(kt[j], ws[j], q0);
        }
#pragma unroll
        for (int j = 8; j < 16; j++) {
            p1 = fmaf(kt[j], wf[j], p1);
            q1 = fmaf(kt[j], ws[j], q1);
        }
        float pf = p0 + p1, ps = q0 + q1;
        float kwf = pf + __shfl_xor(pf, 32);   // combine the two k-halves
        float kws = ps + __shfl_xor(ps, 32);

        float t1 = fmaf(-DF, kwf, cv);            // vt - DF*kWf
        float sv = fmaf(-C1, kws, OMPHI * cv);    // (1-PHI)*vt - C1*kWs

#pragma unroll
        for (int j = 0; j < 16; j++) {
            wf[j] = fmaf(DF, wf[j], kt[j] * t1);                       // Wf_new
            ws[j] = fmaf(C1, ws[j], fmaf(PHI, wf[j], kt[j] * sv));     // uses Wf_new
        }

        kt[0] = na.x; kt[1] = na.y; kt[2] = na.z; kt[3] = na.w;
        kt[4] = nb.x; kt[5] = nb.y; kt[6] = nb.z; kt[7] = nb.w;
        kt[8] = nc.x; kt[9] = nc.y; kt[10] = nc.z; kt[11] = nc.w;
        kt[12] = nd.x; kt[13] = nd.y; kt[14] = nd.z; kt[15] = nd.w;
        cv = nv;
    }

    // Write Ws in reference flatten order: idx = h*1024 + k*32 + v
    float* outp = wsout + (size_t)h * 1024;
#pragma unroll
    for (int j = 0; j < 16; j++)
        outp[(kh * 16 + j) * 32 + v] = ws[j];
}

// ---------------------------------------------------------------------------
// K3: normalize the 12288-float supervector.
// ---------------------------------------------------------------------------
__global__ __launch_bounds__(256) void norm_kernel(
    const float* __restrict__ wsin, float* __restrict__ out)
{
    const int tid = threadIdx.x;
    const float4* in4 = reinterpret_cast<const float4*>(wsin);  // 3072 float4

    float ss = 0.f;
#pragma unroll
    for (int it = 0; it < 12; it++) {
        float4 x = in4[tid + 256 * it];
        ss += x.x * x.x + x.y * x.y + x.z * x.z + x.w * x.w;
    }
    ss += __shfl_xor(ss, 1);
    ss += __shfl_xor(ss, 2);
    ss += __shfl_xor(ss, 4);
    ss += __shfl_xor(ss, 8);
    ss += __shfl_xor(ss, 16);
    ss += __shfl_xor(ss, 32);

    __shared__ float wsum[4];
    if ((tid & 63) == 0) wsum[tid >> 6] = ss;
    __syncthreads();
    float tot = wsum[0] + wsum[1] + wsum[2] + wsum[3];
    float sc = 1.0f / fmaxf(sqrtf(tot), 1e-12f);

#pragma unroll
    for (int it = 0; it < 12; it++) {
        float4 x = in4[tid + 256 * it];
        x.x *= sc; x.y *= sc; x.z *= sc; x.w *= sc;
        reinterpret_cast<float4*>(out)[tid + 256 * it] = x;
    }
}

// ---------------------------------------------------------------------------
extern "C" void kernel_launch(void* const* d_in, const int* in_sizes, int n_in,
                              void* d_out, int out_size, void* d_ws, size_t ws_size,
                              hipStream_t stream)
{
    const float* hidden  = (const float*)d_in[0];
    const float* key_w   = (const float*)d_in[1];
    const float* value_w = (const float*)d_in[2];

    float* kv    = (float*)d_ws;                         // 12*81*64*4 = 243 KB
    float* wsout = (float*)((char*)d_ws + WSOUT_OFF);    // 48 KB

    proj_kernel<<<NWIN, 768, 0, stream>>>(hidden, key_w, value_w, kv);
    scan_kernel<<<NHEAD, 64, 0, stream>>>(kv, wsout);
    norm_kernel<<<1, 256, 0, stream>>>(wsout, (float*)d_out);
}

// Round 9
// 102.059 us; speedup vs baseline: 1.4939x; 1.3665x over previous
//
#include <hip/hip_runtime.h>
#include <math.h>

// ---------------------------------------------------------------------------
// LAMForMTEBSuper: two-timescale decaying associative memory + doc supervector.
//
// Math: kn unit-norm => v_fast == v_slow => flux == 0.1*sigmoid(-0.5) = PHI.
// Heads decouple; recurrence contracts by c1 = 0.85*(1-PHI) = 0.81791/step.
// Start from zero state NWIN=80 tokens before the end: c1^80 ~ 1e-7 relative
// truncation (absmax measured 3.8e-6 at this setting, R6, passed).
//
// R6 post-mortem: proj v1/v2 both ~45 us, txn-throughput-bound — per-thread
// weight-row reads put 64 distinct cache lines under every wave load instr.
// v3: 16-lane groups read rows interleaved (lane ii takes float4 ii+16c) ->
// every load instr covers 16 fully-used contiguous lines. shfl_xor reduce.
// R7 audit fix: V block count was 240 (rows 384..767 OOB); correct is 120.
// R8: second audit clean; resubmitted unchanged (GPU never acquired).
// ---------------------------------------------------------------------------

#define T_TOK 16384
#define DMODEL 384
#define NHEAD 12
#define NWIN 80
#define TT 8              // tokens per proj block
#define NTILES (NWIN / TT)            // 10
#define KBLOCKS (NHEAD * NTILES)      // 120 (K); V is another 120

#define DF 0.3f
#define PHI 0.03775406687981455f      // 0.1/(1+e^0.5)
#define OMPHI 0.96224593312018545f    // 1-PHI
#define C1 0.81790904315215763f       // 0.85*(1-PHI)

#define WSOUT_OFF (512 * 1024)

// ---------------------------------------------------------------------------
// K1 v3: coalesced projection. 240 blocks x 512 threads.
// Blocks 0..119: K (head h = bid/10, token-tile tt = bid%10) — includes k-norm.
// Blocks 120..239: V (row-tile rt = (bid-120)/10, token-tile tt = ...%10).
// Each block: 32 output rows x 8 tokens. Lane decode: wave w (tid>>6),
// group g ((tid>>4)&3), ii (tid&15); row_local = w*4+g.
// Weight read: lane ii loads float4 indices {ii+16c} of its row -> per
// instruction: 4 rows x 256B contiguous = 16 fully-used cache lines.
// ---------------------------------------------------------------------------
__global__ __launch_bounds__(512) void proj_kernel(
    const float* __restrict__ hidden, const float* __restrict__ key_w,
    const float* __restrict__ value_w, float* __restrict__ kv)
{
    __shared__ float hid[TT * DMODEL];     // 12 KB
    __shared__ float kbuf[TT][32];
    __shared__ float scl[TT];

    const int tid = threadIdx.x;
    const int bid = blockIdx.x;
    const bool isK = (bid < KBLOCKS);

    int rowbase, tt;
    if (isK) { rowbase = (bid / NTILES) * 32; tt = bid % NTILES; }
    else     { int vb = bid - KBLOCKS; rowbase = (vb / NTILES) * 32; tt = vb % NTILES; }
    const int t0 = tt * TT;

    // Stage 8 consecutive tokens (contiguous rows of hidden) into LDS.
    {
        const float4* hsrc = reinterpret_cast<const float4*>(
            hidden + (size_t)(T_TOK - NWIN + t0) * DMODEL);
        float4* hdst = reinterpret_cast<float4*>(hid);
#pragma unroll
        for (int idx = tid; idx < TT * DMODEL / 4; idx += 512)
            hdst[idx] = hsrc[idx];
    }
    __syncthreads();

    const int l = tid & 63;
    const int w = tid >> 6;
    const int g = l >> 4;
    const int ii = l & 15;
    const int row_local = w * 4 + g;       // 0..31
    const int row = rowbase + row_local;

    // Coalesced weight load: 6 float4 per lane, interleaved by 16.
    const float4* w4 = reinterpret_cast<const float4*>(
        (isK ? key_w : value_w) + (size_t)row * DMODEL);
    float4 wv0 = w4[ii];
    float4 wv1 = w4[ii + 16];
    float4 wv2 = w4[ii + 32];
    float4 wv3 = w4[ii + 48];
    float4 wv4_ = w4[ii + 64];
    float4 wv5 = w4[ii + 80];

    const float4* h4 = reinterpret_cast<const float4*>(hid);
    float acc[TT];
#pragma unroll
    for (int t = 0; t < TT; t++) acc[t] = 0.f;

#pragma unroll
    for (int t = 0; t < TT; t++) {
        const float4* ht = h4 + t * (DMODEL / 4);
        float4 x;
        x = ht[ii];      acc[t] = fmaf(wv0.x, x.x, fmaf(wv0.y, x.y, fmaf(wv0.z, x.z, fmaf(wv0.w, x.w, acc[t]))));
        x = ht[ii + 16]; acc[t] = fmaf(wv1.x, x.x, fmaf(wv1.y, x.y, fmaf(wv1.z, x.z, fmaf(wv1.w, x.w, acc[t]))));
        x = ht[ii + 32]; acc[t] = fmaf(wv2.x, x.x, fmaf(wv2.y, x.y, fmaf(wv2.z, x.z, fmaf(wv2.w, x.w, acc[t]))));
        x = ht[ii + 48]; acc[t] = fmaf(wv3.x, x.x, fmaf(wv3.y, x.y, fmaf(wv3.z, x.z, fmaf(wv3.w, x.w, acc[t]))));
        x = ht[ii + 64]; acc[t] = fmaf(wv4_.x, x.x, fmaf(wv4_.y, x.y, fmaf(wv4_.z, x.z, fmaf(wv4_.w, x.w, acc[t]))));
        x = ht[ii + 80]; acc[t] = fmaf(wv5.x, x.x, fmaf(wv5.y, x.y, fmaf(wv5.z, x.z, fmaf(wv5.w, x.w, acc[t]))));
    }

    // Butterfly reduce within each 16-lane group (all lanes end with the sum).
#pragma unroll
    for (int t = 0; t < TT; t++) {
        acc[t] += __shfl_xor(acc[t], 1);
        acc[t] += __shfl_xor(acc[t], 2);
        acc[t] += __shfl_xor(acc[t], 4);
        acc[t] += __shfl_xor(acc[t], 8);
    }

    if (isK) {
        const int h = rowbase >> 5;
        if (ii == 0) {
#pragma unroll
            for (int t = 0; t < TT; t++) kbuf[t][row_local] = acc[t];
        }
        __syncthreads();
        if (tid < TT) {
            float ss = 0.f;
#pragma unroll
            for (int r = 0; r < 32; r++) { float x = kbuf[tid][r]; ss = fmaf(x, x, ss); }
            scl[tid] = 1.0f / fmaxf(sqrtf(ss), 1e-12f);
        }
        __syncthreads();
        if (ii == 0) {
#pragma unroll
            for (int t = 0; t < TT; t++)
                kv[((size_t)h * (NWIN + 1) + t0 + t) * 64 + row_local] = acc[t] * scl[t];
        }
    } else {
        const int h = row >> 5;
        const int i = row & 31;
        if (ii == 0) {
#pragma unroll
            for (int t = 0; t < TT; t++)
                kv[((size_t)h * (NWIN + 1) + t0 + t) * 64 + 32 + i] = acc[t];
        }
    }
}

// ---------------------------------------------------------------------------
// K2: per-head sequential scan, 1 wave per head (validated R5/R6, unchanged).
// ---------------------------------------------------------------------------
__global__ __launch_bounds__(64) void scan_kernel(
    const float* __restrict__ kv, float* __restrict__ wsout)
{
    const int h = blockIdx.x;
    const int lane = threadIdx.x;
    const int v = lane & 31;
    const int kh = lane >> 5;

    const float* p = kv + (size_t)h * (NWIN + 1) * 64;

    float kt[16];
    float cv;
    {
        const float4* r4 = reinterpret_cast<const float4*>(p) + kh * 4;
        float4 a = r4[0], b = r4[1], c = r4[2], d = r4[3];
        kt[0] = a.x; kt[1] = a.y; kt[2] = a.z; kt[3] = a.w;
        kt[4] = b.x; kt[5] = b.y; kt[6] = b.z; kt[7] = b.w;
        kt[8] = c.x; kt[9] = c.y; kt[10] = c.z; kt[11] = c.w;
        kt[12] = d.x; kt[13] = d.y; kt[14] = d.z; kt[15] = d.w;
        cv = p[32 + v];
    }

    float wf[16], ws[16];
#pragma unroll
    for (int j = 0; j < 16; j++) { wf[j] = 0.f; ws[j] = 0.f; }

#pragma unroll 2
    for (int t = 0; t < NWIN; t++) {
        const float* nrow = p + (size_t)(t + 1) * 64;
        const float4* n4 = reinterpret_cast<const float4*>(nrow) + kh * 4;
        float4 na = n4[0], nb = n4[1], nc = n4[2], nd = n4[3];
        float nv = nrow[32 + v];

        float p0 = 0.f, p1 = 0.f, q0 = 0.f, q1 = 0.f;
#pragma unroll
        for (int j = 0; j < 8; j++) {
            p0 = fmaf(kt[j], wf[j], p0);
            q0 = fmaf(kt[j], ws[j], q0);
        }
#pragma unroll
        for (int j = 8; j < 16; j++) {
            p1 = fmaf(kt[j], wf[j], p1);
            q1 = fmaf(kt[j], ws[j], q1);
        }
        float pf = p0 + p1, ps = q0 + q1;
        float kwf = pf + __shfl_xor(pf, 32);
        float kws = ps + __shfl_xor(ps, 32);

        float t1 = fmaf(-DF, kwf, cv);            // vt - DF*kWf
        float sv = fmaf(-C1, kws, OMPHI * cv);    // (1-PHI)*vt - C1*kWs

#pragma unroll
        for (int j = 0; j < 16; j++) {
            wf[j] = fmaf(DF, wf[j], kt[j] * t1);                       // Wf_new
            ws[j] = fmaf(C1, ws[j], fmaf(PHI, wf[j], kt[j] * sv));     // uses Wf_new
        }

        kt[0] = na.x; kt[1] = na.y; kt[2] = na.z; kt[3] = na.w;
        kt[4] = nb.x; kt[5] = nb.y; kt[6] = nb.z; kt[7] = nb.w;
        kt[8] = nc.x; kt[9] = nc.y; kt[10] = nc.z; kt[11] = nc.w;
        kt[12] = nd.x; kt[13] = nd.y; kt[14] = nd.z; kt[15] = nd.w;
        cv = nv;
    }

    float* outp = wsout + (size_t)h * 1024;
#pragma unroll
    for (int j = 0; j < 16; j++)
        outp[(kh * 16 + j) * 32 + v] = ws[j];
}

// ---------------------------------------------------------------------------
// K3: normalize the 12288-float supervector (unchanged).
// ---------------------------------------------------------------------------
__global__ __launch_bounds__(256) void norm_kernel(
    const float* __restrict__ wsin, float* __restrict__ out)
{
    const int tid = threadIdx.x;
    const float4* in4 = reinterpret_cast<const float4*>(wsin);

    float ss = 0.f;
#pragma unroll
    for (int it = 0; it < 12; it++) {
        float4 x = in4[tid + 256 * it];
        ss += x.x * x.x + x.y * x.y + x.z * x.z + x.w * x.w;
    }
    ss += __shfl_xor(ss, 1);
    ss += __shfl_xor(ss, 2);
    ss += __shfl_xor(ss, 4);
    ss += __shfl_xor(ss, 8);
    ss += __shfl_xor(ss, 16);
    ss += __shfl_xor(ss, 32);

    __shared__ float wsum[4];
    if ((tid & 63) == 0) wsum[tid >> 6] = ss;
    __syncthreads();
    float tot = wsum[0] + wsum[1] + wsum[2] + wsum[3];
    float sc = 1.0f / fmaxf(sqrtf(tot), 1e-12f);

#pragma unroll
    for (int it = 0; it < 12; it++) {
        float4 x = in4[tid + 256 * it];
        x.x *= sc; x.y *= sc; x.z *= sc; x.w *= sc;
        reinterpret_cast<float4*>(out)[tid + 256 * it] = x;
    }
}

// ---------------------------------------------------------------------------
extern "C" void kernel_launch(void* const* d_in, const int* in_sizes, int n_in,
                              void* d_out, int out_size, void* d_ws, size_t ws_size,
                              hipStream_t stream)
{
    const float* hidden  = (const float*)d_in[0];
    const float* key_w   = (const float*)d_in[1];
    const float* value_w = (const float*)d_in[2];

    float* kv    = (float*)d_ws;                         // 12*81*64*4 = 243 KB
    float* wsout = (float*)((char*)d_ws + WSOUT_OFF);    // 48 KB

    proj_kernel<<<2 * KBLOCKS, 512, 0, stream>>>(hidden, key_w, value_w, kv);
    scan_kernel<<<NHEAD, 64, 0, stream>>>(kv, wsout);
    norm_kernel<<<1, 256, 0, stream>>>(wsout, (float*)d_out);
}

// Round 12
// 93.847 us; speedup vs baseline: 1.6246x; 1.0875x over previous
//
#include <hip/hip_runtime.h>
#include <math.h>

// ---------------------------------------------------------------------------
// LAMForMTEBSuper: two-timescale decaying associative memory + doc supervector.
//
// Math: kn unit-norm => v_fast == v_slow => flux == 0.1*sigmoid(-0.5) = PHI.
// Heads decouple; recurrence contracts by c1 = 0.85*(1-PHI) = 0.81791/step.
// Start from zero state NWIN=80 tokens before the end: truncation-dominated
// absmax 3.8e-6 (R6/R9, passed).
//
// R9 post-mortem: proj coalescing confirmed (proj ~45 -> <~7 us, dur 139->102).
// Budget: ~45 us ws-poison fill + ~8 us input restore are harness-fixed;
// scan is the largest controllable piece (est 25-30 us).
// R10/R11: scan critical path — (a) __shfl_xor(,32) -> v_permlane32_swap_b32
// (VALU-rate vs ds_bpermute LDS-latency), (b) float2 packed math (v_pk_fma).
// R11 audit fix: "+&v" early-clobber on the swap's first operand — with both
// operands holding the same value, regalloc could alias them to ONE register
// (v_permlane32_swap_b32 v5,v5 = in-place half swap => wrong pair-sum).
// R12: third audit (swap-semantics direction-agnosticism re-derived) clean;
// resubmitted unchanged (GPU never acquired).
// ---------------------------------------------------------------------------

#define T_TOK 16384
#define DMODEL 384
#define NHEAD 12
#define NWIN 80
#define TT 8              // tokens per proj block
#define NTILES (NWIN / TT)            // 10
#define KBLOCKS (NHEAD * NTILES)      // 120 (K); V is another 120

#define DF 0.3f
#define PHI 0.03775406687981455f      // 0.1/(1+e^0.5)
#define OMPHI 0.96224593312018545f    // 1-PHI
#define C1 0.81790904315215763f       // 0.85*(1-PHI)

#define WSOUT_OFF (512 * 1024)

typedef float v2f __attribute__((ext_vector_type(2)));

// ---------------------------------------------------------------------------
// K1 v3: coalesced projection (validated R9: dropped out of top-5).
// 240 blocks x 512 threads. Blocks 0..119: K (+k-norm); 120..239: V.
// 16-lane groups share one output row, lane ii takes float4 {ii+16c} ->
// every weight load instr covers 16 fully-used contiguous cache lines.
// ---------------------------------------------------------------------------
__global__ __launch_bounds__(512) void proj_kernel(
    const float* __restrict__ hidden, const float* __restrict__ key_w,
    const float* __restrict__ value_w, float* __restrict__ kv)
{
    __shared__ float hid[TT * DMODEL];     // 12 KB
    __shared__ float kbuf[TT][32];
    __shared__ float scl[TT];

    const int tid = threadIdx.x;
    const int bid = blockIdx.x;
    const bool isK = (bid < KBLOCKS);

    int rowbase, tt;
    if (isK) { rowbase = (bid / NTILES) * 32; tt = bid % NTILES; }
    else     { int vb = bid - KBLOCKS; rowbase = (vb / NTILES) * 32; tt = vb % NTILES; }
    const int t0 = tt * TT;

    {
        const float4* hsrc = reinterpret_cast<const float4*>(
            hidden + (size_t)(T_TOK - NWIN + t0) * DMODEL);
        float4* hdst = reinterpret_cast<float4*>(hid);
#pragma unroll
        for (int idx = tid; idx < TT * DMODEL / 4; idx += 512)
            hdst[idx] = hsrc[idx];
    }
    __syncthreads();

    const int l = tid & 63;
    const int w = tid >> 6;
    const int g = l >> 4;
    const int ii = l & 15;
    const int row_local = w * 4 + g;       // 0..31
    const int row = rowbase + row_local;

    const float4* w4 = reinterpret_cast<const float4*>(
        (isK ? key_w : value_w) + (size_t)row * DMODEL);
    float4 wv0 = w4[ii];
    float4 wv1 = w4[ii + 16];
    float4 wv2 = w4[ii + 32];
    float4 wv3 = w4[ii + 48];
    float4 wv4_ = w4[ii + 64];
    float4 wv5 = w4[ii + 80];

    const float4* h4 = reinterpret_cast<const float4*>(hid);
    float acc[TT];
#pragma unroll
    for (int t = 0; t < TT; t++) acc[t] = 0.f;

#pragma unroll
    for (int t = 0; t < TT; t++) {
        const float4* ht = h4 + t * (DMODEL / 4);
        float4 x;
        x = ht[ii];      acc[t] = fmaf(wv0.x, x.x, fmaf(wv0.y, x.y, fmaf(wv0.z, x.z, fmaf(wv0.w, x.w, acc[t]))));
        x = ht[ii + 16]; acc[t] = fmaf(wv1.x, x.x, fmaf(wv1.y, x.y, fmaf(wv1.z, x.z, fmaf(wv1.w, x.w, acc[t]))));
        x = ht[ii + 32]; acc[t] = fmaf(wv2.x, x.x, fmaf(wv2.y, x.y, fmaf(wv2.z, x.z, fmaf(wv2.w, x.w, acc[t]))));
        x = ht[ii + 48]; acc[t] = fmaf(wv3.x, x.x, fmaf(wv3.y, x.y, fmaf(wv3.z, x.z, fmaf(wv3.w, x.w, acc[t]))));
        x = ht[ii + 64]; acc[t] = fmaf(wv4_.x, x.x, fmaf(wv4_.y, x.y, fmaf(wv4_.z, x.z, fmaf(wv4_.w, x.w, acc[t]))));
        x = ht[ii + 80]; acc[t] = fmaf(wv5.x, x.x, fmaf(wv5.y, x.y, fmaf(wv5.z, x.z, fmaf(wv5.w, x.w, acc[t]))));
    }

#pragma unroll
    for (int t = 0; t < TT; t++) {
        acc[t] += __shfl_xor(acc[t], 1);
        acc[t] += __shfl_xor(acc[t], 2);
        acc[t] += __shfl_xor(acc[t], 4);
        acc[t] += __shfl_xor(acc[t], 8);
    }

    if (isK) {
        const int h = rowbase >> 5;
        if (ii == 0) {
#pragma unroll
            for (int t = 0; t < TT; t++) kbuf[t][row_local] = acc[t];
        }
        __syncthreads();
        if (tid < TT) {
            float ss = 0.f;
#pragma unroll
            for (int r = 0; r < 32; r++) { float x = kbuf[tid][r]; ss = fmaf(x, x, ss); }
            scl[tid] = 1.0f / fmaxf(sqrtf(ss), 1e-12f);
        }
        __syncthreads();
        if (ii == 0) {
#pragma unroll
            for (int t = 0; t < TT; t++)
                kv[((size_t)h * (NWIN + 1) + t0 + t) * 64 + row_local] = acc[t] * scl[t];
        }
    } else {
        const int h = row >> 5;
        const int i = row & 31;
        if (ii == 0) {
#pragma unroll
            for (int t = 0; t < TT; t++)
                kv[((size_t)h * (NWIN + 1) + t0 + t) * 64 + 32 + i] = acc[t];
        }
    }
}

// ---------------------------------------------------------------------------
// K2 v2: per-head scan, 1 wave/head, lane = (v, khalf). State as float2
// ext-vectors (v_pk_fma_f32); cross-half dot combine via
// v_permlane32_swap_b32 (D+S is the lane-pair sum in ALL lanes under either
// swap-direction semantic; "+&v" forces distinct regs — see header).
//   Wf <- DF*Wf + kt*(vt - DF*kWf)
//   Ws <- C1*Ws + kt*(OMPHI*vt - C1*kWs) + PHI*Wf_new
// kt v2f index j: k = kh*16 + 2*j + e (e = component).
// ---------------------------------------------------------------------------
__global__ __launch_bounds__(64) void scan_kernel(
    const float* __restrict__ kv, float* __restrict__ wsout)
{
    const int h = blockIdx.x;
    const int lane = threadIdx.x;
    const int v = lane & 31;
    const int kh = lane >> 5;

    const float* p = kv + (size_t)h * (NWIN + 1) * 64;

    v2f kt[8];
    float cv;
    {
        const float4* r4 = reinterpret_cast<const float4*>(p) + kh * 4;
        float4 a = r4[0], b = r4[1], c = r4[2], d = r4[3];
        kt[0] = (v2f){a.x, a.y}; kt[1] = (v2f){a.z, a.w};
        kt[2] = (v2f){b.x, b.y}; kt[3] = (v2f){b.z, b.w};
        kt[4] = (v2f){c.x, c.y}; kt[5] = (v2f){c.z, c.w};
        kt[6] = (v2f){d.x, d.y}; kt[7] = (v2f){d.z, d.w};
        cv = p[32 + v];
    }

    v2f wf[8], ws[8];
#pragma unroll
    for (int j = 0; j < 8; j++) { wf[j] = (v2f){0.f, 0.f}; ws[j] = (v2f){0.f, 0.f}; }

    const v2f dfv = (v2f){DF, DF};
    const v2f c1v = (v2f){C1, C1};
    const v2f phiv = (v2f){PHI, PHI};

#pragma unroll 2
    for (int t = 0; t < NWIN; t++) {
        // Prefetch next token (row NWIN is a legal pad; loaded, never consumed).
        const float* nrow = p + (size_t)(t + 1) * 64;
        const float4* n4 = reinterpret_cast<const float4*>(nrow) + kh * 4;
        float4 na = n4[0], nb = n4[1], nc = n4[2], nd = n4[3];
        float nv = nrow[32 + v];

        // Packed partial dots over this lane's 16 k's (2 accums for ILP).
        v2f P0 = (v2f){0.f, 0.f}, P1 = P0, Q0 = P0, Q1 = P0;
#pragma unroll
        for (int j = 0; j < 4; j++) {
            P0 = kt[j] * wf[j] + P0;
            Q0 = kt[j] * ws[j] + Q0;
        }
#pragma unroll
        for (int j = 4; j < 8; j++) {
            P1 = kt[j] * wf[j] + P1;
            Q1 = kt[j] * ws[j] + Q1;
        }
        float pf = (P0.x + P0.y) + (P1.x + P1.y);
        float ps = (Q0.x + Q0.y) + (Q1.x + Q1.y);

        // Cross-half combine. "+&v" early-clobber: pd must NOT share psrc's
        // register (same initial value => regalloc could alias them; an
        // in-place v_permlane32_swap_b32 v,v would be a silent miscompile).
        float pd = pf, psrc = pf;
        asm volatile("v_permlane32_swap_b32 %0, %1" : "+&v"(pd), "+v"(psrc));
        float kwf = pd + psrc;
        float qd = ps, qsrc = ps;
        asm volatile("v_permlane32_swap_b32 %0, %1" : "+&v"(qd), "+v"(qsrc));
        float kws = qd + qsrc;

        float t1 = fmaf(-DF, kwf, cv);            // vt - DF*kWf
        float sv = fmaf(-C1, kws, OMPHI * cv);    // (1-PHI)*vt - C1*kWs
        const v2f t1v = (v2f){t1, t1};
        const v2f svv = (v2f){sv, sv};

#pragma unroll
        for (int j = 0; j < 8; j++) {
            wf[j] = dfv * wf[j] + kt[j] * t1v;                  // Wf_new
            ws[j] = c1v * ws[j] + (phiv * wf[j] + kt[j] * svv); // uses Wf_new
        }

        kt[0] = (v2f){na.x, na.y}; kt[1] = (v2f){na.z, na.w};
        kt[2] = (v2f){nb.x, nb.y}; kt[3] = (v2f){nb.z, nb.w};
        kt[4] = (v2f){nc.x, nc.y}; kt[5] = (v2f){nc.z, nc.w};
        kt[6] = (v2f){nd.x, nd.y}; kt[7] = (v2f){nd.z, nd.w};
        cv = nv;
    }

    // Reference flatten order: idx = h*1024 + k*32 + v, k = kh*16 + 2*j + e.
    float* outp = wsout + (size_t)h * 1024;
#pragma unroll
    for (int j = 0; j < 8; j++) {
        outp[(kh * 16 + 2 * j) * 32 + v]     = ws[j].x;
        outp[(kh * 16 + 2 * j + 1) * 32 + v] = ws[j].y;
    }
}

// ---------------------------------------------------------------------------
// K3: normalize the 12288-float supervector (unchanged).
// ---------------------------------------------------------------------------
__global__ __launch_bounds__(256) void norm_kernel(
    const float* __restrict__ wsin, float* __restrict__ out)
{
    const int tid = threadIdx.x;
    const float4* in4 = reinterpret_cast<const float4*>(wsin);

    float ss = 0.f;
#pragma unroll
    for (int it = 0; it < 12; it++) {
        float4 x = in4[tid + 256 * it];
        ss += x.x * x.x + x.y * x.y + x.z * x.z + x.w * x.w;
    }
    ss += __shfl_xor(ss, 1);
    ss += __shfl_xor(ss, 2);
    ss += __shfl_xor(ss, 4);
    ss += __shfl_xor(ss, 8);
    ss += __shfl_xor(ss, 16);
    ss += __shfl_xor(ss, 32);

    __shared__ float wsum[4];
    if ((tid & 63) == 0) wsum[tid >> 6] = ss;
    __syncthreads();
    float tot = wsum[0] + wsum[1] + wsum[2] + wsum[3];
    float sc = 1.0f / fmaxf(sqrtf(tot), 1e-12f);

#pragma unroll
    for (int it = 0; it < 12; it++) {
        float4 x = in4[tid + 256 * it];
        x.x *= sc; x.y *= sc; x.z *= sc; x.w *= sc;
        reinterpret_cast<float4*>(out)[tid + 256 * it] = x;
    }
}

// ---------------------------------------------------------------------------
extern "C" void kernel_launch(void* const* d_in, const int* in_sizes, int n_in,
                              void* d_out, int out_size, void* d_ws, size_t ws_size,
                              hipStream_t stream)
{
    const float* hidden  = (const float*)d_in[0];
    const float* key_w   = (const float*)d_in[1];
    const float* value_w = (const float*)d_in[2];

    float* kv    = (float*)d_ws;                         // 12*81*64*4 = 243 KB
    float* wsout = (float*)((char*)d_ws + WSOUT_OFF);    // 48 KB

    proj_kernel<<<2 * KBLOCKS, 512, 0, stream>>>(hidden, key_w, value_w, kv);
    scan_kernel<<<NHEAD, 64, 0, stream>>>(kv, wsout);
    norm_kernel<<<1, 256, 0, stream>>>(wsout, (float*)d_out);
}